// Round 13
// baseline (181.824 us; speedup 1.0000x reference)
//
#include <hip/hip_runtime.h>

// TeamMovementModel R13: R12 fused kernel + VALU-issue diet.
// R12 counters: total-kernel gap (~64us) is harness-fixed; kernel 116us =
// 2119 cyc/step, VALU+trans issue ~1060 cyc/SIMD/step is the biggest term.
// Cuts vs R12 (epilogue algebra only; LSTM structure & numerics class same):
//  1. Merged-rcp: i*g and o*tanh(c) each use ONE rcp of the product of
//     denominators (20 -> 16 trans/lane). c clamped to +-15 (tanh(15)=1 in
//     fp32) so e^{2c} can't reach inf -> no inf/inf.
//  2. f32x2 packed pairs -> v_pk_mul/add/fma_f32 on gfx950.
//  3. Bank-masked DPP (bank_mask 0xC): one dpp does select+swap (drops 8
//     cndmask); zero4 C-operand kills the 16 per-step acc-init movs (R11).

#define HDIM 128
#define TSTEPS 128
#define NPLAYER 1408
#define NSEQ 1472
#define NB 8
#define NBLK (NSEQ / NB)        // 184
#define NPBLK (NPLAYER / NB)    // 176
#define KT 5                    // k-tiles of 32 (K_aug = 160)
#define BSTR 168                // fp16 per B row (336 B stride)
#define XSTR 258                // floats per x col
#define HSTR 132                // floats per hbuf row

typedef _Float16 f16x8 __attribute__((ext_vector_type(8)));
typedef _Float16 f16x2 __attribute__((ext_vector_type(2)));
typedef float    f32x4 __attribute__((ext_vector_type(4)));
typedef float    f32x2 __attribute__((ext_vector_type(2)));

#define LOG2E 1.44269504f

__device__ __forceinline__ f32x2 exp2v(f32x2 a) {
    return (f32x2){__builtin_amdgcn_exp2f(a[0]), __builtin_amdgcn_exp2f(a[1])};
}
__device__ __forceinline__ f32x2 rcpv(f32x2 a) {
    return (f32x2){__builtin_amdgcn_rcpf(a[0]), __builtin_amdgcn_rcpf(a[1])};
}
// select+swap in one DPP: lanes nn<8 keep `keep`, lanes nn>=8 get swap-partner
// (lane^8 within each 16) value of `src`. bank_mask 0xC writes only banks 2,3
// (lanes 8..15 per row-16); masked lanes retain `keep` (the builtin's old).
__device__ __forceinline__ float dpp_sel8(float keep, float src) {
    return __int_as_float(__builtin_amdgcn_update_dpp(
        __float_as_int(keep), __float_as_int(src), 0x128 /*ror:8*/,
        0xF, 0xC, false));
}

__global__ void __launch_bounds__(512)
__attribute__((amdgpu_waves_per_eu(2, 2)))
lstm_fc_kernel(const float* __restrict__ x_players, const float* __restrict__ x_ball,
               const float* __restrict__ p_w_ih, const float* __restrict__ p_w_hh,
               const float* __restrict__ p_b_ih, const float* __restrict__ p_b_hh,
               const float* __restrict__ b_w_ih, const float* __restrict__ b_w_hh,
               const float* __restrict__ b_b_ih, const float* __restrict__ b_b_hh,
               const float* __restrict__ fc_w, const float* __restrict__ fc_b,
               float* __restrict__ out)
{
    const int tid  = threadIdx.x;
    const int blk  = blockIdx.x;          // 0..183; 176..183 ball
    const int w    = tid >> 6;            // wave -> h-rows [16w, 16w+16)
    const int lane = tid & 63;
    const int nn   = lane & 15;           // MFMA n (col)
    const int q    = lane >> 4;           // MFMA quad

    const bool ball = (blk >= NPBLK);
    const float* w_ih = ball ? b_w_ih : p_w_ih;
    const float* w_hh = ball ? b_w_hh : p_w_hh;
    const float* bih  = ball ? b_b_ih : p_b_ih;
    const float* bhh  = ball ? b_b_hh : p_b_hh;
    const float* xg   = ball ? (x_ball    + (size_t)(blk - NPBLK) * NB * TSTEPS * 2)
                             : (x_players + (size_t)blk * NB * TSTEPS * 2);

    __shared__ __align__(16) _Float16 b_sh[2][NB * BSTR];
    __shared__ __align__(16) float x_sh[NB * XSTR];
    __shared__ __align__(16) float hbuf[NB * HSTR];   // final h, fp32
    __shared__ float vout[NB * 40];                   // ball-path fc part

    for (int i = tid; i < NB * 256; i += 512)
        x_sh[(i >> 8) * XSTR + (i & 255)] = xg[i];
    for (int i = tid; i < 2 * NB * BSTR / 2; i += 512)
        ((int*)b_sh)[i] = 0;

    // ---- A fragments: gate mi, row r = mi*128 + 16w + nn.
    // a[j] = A[m=lane&15][k = 32kt + 8q + j]; kt=4 aug: k=128:wi0 129:wi1 130:bias
    f16x8 afr[4][KT];
    #pragma unroll
    for (int mi = 0; mi < 4; ++mi) {
        const int r = mi * HDIM + w * 16 + nn;
        const float* wr = w_hh + (size_t)r * HDIM;
        #pragma unroll
        for (int kt = 0; kt < 4; ++kt) {
            const float* p = wr + kt * 32 + q * 8;
            f16x8 a8;
            #pragma unroll
            for (int j = 0; j < 8; ++j) a8[j] = (_Float16)p[j];
            afr[mi][kt] = a8;
        }
        f16x8 a8 = {};
        if (q == 0) {
            a8[0] = (_Float16)w_ih[2 * r];
            a8[1] = (_Float16)w_ih[2 * r + 1];
            a8[2] = (_Float16)(bih[r] + bhh[r]);
        }
        afr[mi][4] = a8;
    }

    const int colh   = nn & 7;                  // owned seq col
    const int rowoff = (nn < 8) ? 0 : 2;        // reg-split via DPP
    const int hrow   = w * 16 + 4 * q + rowoff; // first of 2 owned h-rows
    f32x2 c = (f32x2){0.f, 0.f};
    f32x2 h = (f32x2){0.f, 0.f};

    // persistent zero C-operand: aug MFMA writes acc directly (no init movs)
    f32x4 zero4 = (f32x4){0.f, 0.f, 0.f, 0.f};
    asm volatile("" : "+v"(zero4));

    __syncthreads();
    if (tid < NB) {   // x(0) into buf0; '1' aug col into both buffers
        _Float16* br0 = &b_sh[0][tid * BSTR];
        br0[128] = (_Float16)x_sh[tid * XSTR];
        br0[129] = (_Float16)x_sh[tid * XSTR + 1];
        br0[130] = (_Float16)1.0f;
        b_sh[1][tid * BSTR + 130] = (_Float16)1.0f;
    }
    __syncthreads();

    f16x8 bfr[KT] = {};   // lanes nn>=8 keep constant-zero B frags

    auto substep = [&](int s, const _Float16* bc, _Float16* bn, bool last) {
        if (nn < 8) {
            #pragma unroll
            for (int kt = 0; kt < KT; ++kt)
                bfr[kt] = *(const f16x8*)(bc + nn * BSTR + kt * 32 + q * 8);
        }

        f32x4 acc[4];
        // aug tile first: acc = W_ih@x + bias (+zero4)
        #pragma unroll
        for (int mi = 0; mi < 4; ++mi)
            acc[mi] = __builtin_amdgcn_mfma_f32_16x16x32_f16(afr[mi][4], bfr[4], zero4, 0, 0, 0);
        #pragma unroll
        for (int kt = 0; kt < 4; ++kt)
            #pragma unroll
            for (int mi = 0; mi < 4; ++mi)
                acc[mi] = __builtin_amdgcn_mfma_f32_16x16x32_f16(afr[mi][kt], bfr[kt], acc[mi], 0, 0, 0);

        if (!last && tid < NB) {
            const float x0 = x_sh[tid * XSTR + 2 * (s + 1)];
            const float x1 = x_sh[tid * XSTR + 2 * (s + 1) + 1];
            *(f16x2*)&bn[tid * BSTR + 128] = (f16x2){(_Float16)x0, (_Float16)x1};
        }

        // select+swap in one DPP per value: lane nn<8 keeps regs {0,1} of col
        // nn; lane nn>=8 receives partner's regs {2,3} of col nn-8.
        f32x2 u[4];
        #pragma unroll
        for (int mi = 0; mi < 4; ++mi) {
            u[mi][0] = dpp_sel8(acc[mi][0], acc[mi][2]);
            u[mi][1] = dpp_sel8(acc[mi][1], acc[mi][3]);
        }

        // merged-rcp LSTM cell (packed pairs):
        // i*g      = (eg-1) / ((1+ei)(eg+1)),  ei=e^{-ui}, eg=e^{2ug}
        // f        = 1/(1+ef)
        // o*tanh(c)= (ec-1) / ((1+eo)(ec+1)),  ec=e^{2c}
        const f32x2 ei = exp2v(u[0] * -LOG2E);
        const f32x2 ef = exp2v(u[1] * -LOG2E);
        const f32x2 eg = exp2v(u[2] * (2.0f * LOG2E));
        const f32x2 eo = exp2v(u[3] * -LOG2E);
        const f32x2 ig = (eg - 1.0f) * rcpv((ei + 1.0f) * (eg + 1.0f));
        const f32x2 ff = rcpv(ef + 1.0f);
        c = __builtin_elementwise_fma(ff, c, ig);
        c = __builtin_elementwise_min(__builtin_elementwise_max(c, (f32x2){-15.f, -15.f}),
                                      (f32x2){15.f, 15.f});
        const f32x2 ec = exp2v(c * (2.0f * LOG2E));
        h = (ec - 1.0f) * rcpv((eo + 1.0f) * (ec + 1.0f));

        if (!last) {
            *(f16x2*)&bn[colh * BSTR + hrow] = (f16x2){(_Float16)h[0], (_Float16)h[1]};
            __syncthreads();
        }
    };

    _Float16* b0 = &b_sh[0][0];
    _Float16* b1 = &b_sh[1][0];
    #pragma unroll 1
    for (int it = 0; it < TSTEPS / 2 - 1; ++it) {   // steps 0..125
        substep(2 * it,     b0, b1, false);
        substep(2 * it + 1, b1, b0, false);
        // loop-carried AGPR pins: block rematerialization (R1..R5 failure mode)
        asm volatile("" : "+a"(afr[0][0]), "+a"(afr[0][1]), "+a"(afr[0][2]), "+a"(afr[0][3]), "+a"(afr[0][4]));
        asm volatile("" : "+a"(afr[1][0]), "+a"(afr[1][1]), "+a"(afr[1][2]), "+a"(afr[1][3]), "+a"(afr[1][4]));
        asm volatile("" : "+a"(afr[2][0]), "+a"(afr[2][1]), "+a"(afr[2][2]), "+a"(afr[2][3]), "+a"(afr[2][4]));
        asm volatile("" : "+a"(afr[3][0]), "+a"(afr[3][1]), "+a"(afr[3][2]), "+a"(afr[3][3]), "+a"(afr[3][4]));
        asm volatile("" : "+v"(zero4));
    }
    substep(126, b0, b1, false);
    substep(127, b1, b0, true);    // peeled: no h-write, no barrier

    // ---- final h -> LDS (fp32), then fused FC epilogue ----
    hbuf[colh * HSTR + hrow]     = h[0];
    hbuf[colh * HSTR + hrow + 1] = h[1];
    __syncthreads();

    if (!ball) {
        // player part: out[gp*40+row] += fc_b[row] + fc_w[row, 0:128] . h(gp)
        for (int o = tid; o < NB * 40; o += 512) {
            const int j = o / 40, row = o - j * 40;
            const float* wr = fc_w + (size_t)row * 2 * HDIM;        // cols 0..127
            const float* hp = &hbuf[j * HSTR];
            float a0 = fc_b[row], a1 = 0.f, a2 = 0.f, a3 = 0.f;
            #pragma unroll
            for (int k = 0; k < HDIM; k += 4) {
                float4 wv = *(const float4*)(wr + k);
                float4 hv = *(const float4*)(hp + k);
                a0 = __builtin_fmaf(wv.x, hv.x, a0);
                a1 = __builtin_fmaf(wv.y, hv.y, a1);
                a2 = __builtin_fmaf(wv.z, hv.z, a2);
                a3 = __builtin_fmaf(wv.w, hv.w, a3);
            }
            atomicAdd(&out[(size_t)(NB * blk + j) * 40 + row], (a0 + a1) + (a2 + a3));
        }
    } else {
        // ball part: v[c][row] = fc_w[row, 128:256] . ball_h(batch), then
        // broadcast-add to the batch's 22 players.
        for (int o = tid; o < NB * 40; o += 512) {
            const int cc = o / 40, row = o - cc * 40;
            const float* wr = fc_w + (size_t)row * 2 * HDIM + HDIM;  // cols 128..255
            const float* hp = &hbuf[cc * HSTR];
            float a0 = 0.f, a1 = 0.f, a2 = 0.f, a3 = 0.f;
            #pragma unroll
            for (int k = 0; k < HDIM; k += 4) {
                float4 wv = *(const float4*)(wr + k);
                float4 hv = *(const float4*)(hp + k);
                a0 = __builtin_fmaf(wv.x, hv.x, a0);
                a1 = __builtin_fmaf(wv.y, hv.y, a1);
                a2 = __builtin_fmaf(wv.z, hv.z, a2);
                a3 = __builtin_fmaf(wv.w, hv.w, a3);
            }
            vout[cc * 40 + row] = (a0 + a1) + (a2 + a3);
        }
        __syncthreads();
        const int base_batch = (blk - NPBLK) * NB;
        for (int o = tid; o < NB * 22 * 40; o += 512) {
            const int cc = o / 880, rem = o - cc * 880;
            const int p = rem / 40, row = rem - p * 40;
            atomicAdd(&out[(size_t)((base_batch + cc) * 22 + p) * 40 + row],
                      vout[cc * 40 + row]);
        }
    }
}

extern "C" void kernel_launch(void* const* d_in, const int* in_sizes, int n_in,
                              void* d_out, int out_size, void* d_ws, size_t ws_size,
                              hipStream_t stream) {
    const float* x_players = (const float*)d_in[0];
    const float* x_ball    = (const float*)d_in[1];
    const float* p_w_ih    = (const float*)d_in[2];
    const float* p_w_hh    = (const float*)d_in[3];
    const float* p_b_ih    = (const float*)d_in[4];
    const float* p_b_hh    = (const float*)d_in[5];
    const float* b_w_ih    = (const float*)d_in[6];
    const float* b_w_hh    = (const float*)d_in[7];
    const float* b_b_ih    = (const float*)d_in[8];
    const float* b_b_hh    = (const float*)d_in[9];
    const float* fc_w      = (const float*)d_in[10];
    const float* fc_b      = (const float*)d_in[11];

    // zero the output: both block types accumulate into it atomically
    hipMemsetAsync(d_out, 0, (size_t)out_size * sizeof(float), stream);

    lstm_fc_kernel<<<dim3(NBLK), dim3(512), 0, stream>>>(
        x_players, x_ball, p_w_ih, p_w_hh, p_b_ih, p_b_hh,
        b_w_ih, b_w_hh, b_b_ih, b_b_hh, fc_w, fc_b, (float*)d_out);
}